// Round 4
// baseline (92.758 us; speedup 1.0000x reference)
//
#include <hip/hip_runtime.h>

// x (16384 x 4096 fp32), W (4096 x 4096 fp32)
// out[b] = 0.75 * dot(x[b,:], colsum(W)), shape (16384,1) fp32.
// Memory-bound: 320 MB compulsory read -> ~51 us roofline @ 6.3 TB/s.

#define N_COLS 4096
#define BATCH  16384
#define SCALE  0.75f   // SCALING_FACTOR / 2.0

typedef float f32x4 __attribute__((ext_vector_type(4)));

__device__ __forceinline__ f32x4 ntload4(const float* p) {
    return __builtin_nontemporal_load(reinterpret_cast<const f32x4*>(p));
}

// ---------------- Kernel 1: column-sum of W into ws[0..4095] ----------------
// grid = (4 col-tiles, 256 row-chunks) = 1024 blocks (4/CU, 16 waves/CU).
// Thread owns 4 consecutive cols, accumulates 16 rows in 2 independent
// accumulators (deeper outstanding-load chain), 4 atomicAdds at the end.
__global__ __launch_bounds__(256, 4) void colsum_kernel(const float* __restrict__ W,
                                                        float* __restrict__ ws) {
    const int colBase = blockIdx.x * 1024 + threadIdx.x * 4;
    const int row0    = blockIdx.y * 16;
    f32x4 acc0 = {0.f, 0.f, 0.f, 0.f};
    f32x4 acc1 = {0.f, 0.f, 0.f, 0.f};
#pragma unroll
    for (int r = 0; r < 16; r += 2) {
        acc0 += ntload4(&W[(size_t)(row0 + r + 0) * N_COLS + colBase]);
        acc1 += ntload4(&W[(size_t)(row0 + r + 1) * N_COLS + colBase]);
    }
    const f32x4 acc = acc0 + acc1;
    atomicAdd(&ws[colBase + 0], acc.x);
    atomicAdd(&ws[colBase + 1], acc.y);
    atomicAdd(&ws[colBase + 2], acc.z);
    atomicAdd(&ws[colBase + 3], acc.w);
}

// ---------------- Kernel 2: out[b] = SCALE * dot(x[b,:], ws) ----------------
// 4 rows per wave, 4 waves per block -> 16 rows/block, 1024 blocks
// (4 blocks/CU guaranteed by launch_bounds). Per iter: 1 cached ws load +
// 4 nontemporal x loads (all f32x4), 16 FMAs.
__global__ __launch_bounds__(256, 4) void rowdot_kernel(const float* __restrict__ x,
                                                        const float* __restrict__ ws,
                                                        float* __restrict__ out) {
    const int wave = threadIdx.x >> 6;
    const int lane = threadIdx.x & 63;
    const int row0 = (blockIdx.x * 4 + wave) * 4;   // 4 consecutive rows

    const float* __restrict__ x0 = x + (size_t)(row0 + 0) * N_COLS;
    const float* __restrict__ x1 = x + (size_t)(row0 + 1) * N_COLS;
    const float* __restrict__ x2 = x + (size_t)(row0 + 2) * N_COLS;
    const float* __restrict__ x3 = x + (size_t)(row0 + 3) * N_COLS;

    float a0 = 0.f, a1 = 0.f, a2 = 0.f, a3 = 0.f;
#pragma unroll 8
    for (int i = 0; i < 16; ++i) {
        const int idx = (i * 64 + lane) * 4;
        const f32x4 c  = *reinterpret_cast<const f32x4*>(&ws[idx]); // L1-resident
        const f32x4 v0 = ntload4(&x0[idx]);
        const f32x4 v1 = ntload4(&x1[idx]);
        const f32x4 v2 = ntload4(&x2[idx]);
        const f32x4 v3 = ntload4(&x3[idx]);
        a0 += v0.x * c.x + v0.y * c.y + v0.z * c.z + v0.w * c.w;
        a1 += v1.x * c.x + v1.y * c.y + v1.z * c.z + v1.w * c.w;
        a2 += v2.x * c.x + v2.y * c.y + v2.z * c.z + v2.w * c.w;
        a3 += v3.x * c.x + v3.y * c.y + v3.z * c.z + v3.w * c.w;
    }
#pragma unroll
    for (int off = 32; off >= 1; off >>= 1) {
        a0 += __shfl_down(a0, off, 64);
        a1 += __shfl_down(a1, off, 64);
        a2 += __shfl_down(a2, off, 64);
        a3 += __shfl_down(a3, off, 64);
    }
    if (lane == 0) {
        f32x4 r = {a0 * SCALE, a1 * SCALE, a2 * SCALE, a3 * SCALE};
        *reinterpret_cast<f32x4*>(&out[row0]) = r;
    }
}

extern "C" void kernel_launch(void* const* d_in, const int* in_sizes, int n_in,
                              void* d_out, int out_size, void* d_ws, size_t ws_size,
                              hipStream_t stream) {
    const float* x = (const float*)d_in[0];   // (16384, 4096)
    const float* W = (const float*)d_in[1];   // (4096, 4096)
    float* out = (float*)d_out;               // (16384, 1)
    float* ws  = (float*)d_ws;

    (void)hipMemsetAsync(ws, 0, N_COLS * sizeof(float), stream);
    colsum_kernel<<<dim3(4, 256), 256, 0, stream>>>(W, ws);
    rowdot_kernel<<<BATCH / 16, 256, 0, stream>>>(x, ws, out);
}

// Round 5
// 78.393 us; speedup vs baseline: 1.1832x; 1.1832x over previous
//
#include <hip/hip_runtime.h>

// x (16384 x 4096 fp32), W (4096 x 4096 fp32)
// out[b] = 0.75 * dot(x[b,:], colsum(W)), shape (16384,1) fp32.
// Memory-bound: 320 MB compulsory read -> ~51 us roofline @ 6.3 TB/s.

#define N_COLS 4096
#define BATCH  16384
#define SCALE  0.75f   // SCALING_FACTOR / 2.0

typedef float f32x4 __attribute__((ext_vector_type(4)));

__device__ __forceinline__ f32x4 ntload4(const float* p) {
    return __builtin_nontemporal_load(reinterpret_cast<const f32x4*>(p));
}

// ---------------- Kernel 1: column-sum of W into ws[0..4095] ----------------
// Exclusive columns -> NO atomics, NO memset. grid = 256 blocks (1/CU),
// block = 256. Block owns 16 cols, reads all 4096 rows.
// Thread t: col-chunk (t&3) [4 consecutive cols], row stream (t>>2)+64k.
// Per-wave load instr = 16 rows x 64 B contiguous segments (granule-aligned).
// Reduce: shuffle across row-streams in wave, tiny LDS across 4 waves,
// one 64 B store per block. Idempotent & deterministic.
__global__ __launch_bounds__(256) void colsum_ex_kernel(const float* __restrict__ W,
                                                        float* __restrict__ ws) {
    const int t     = threadIdx.x;
    const int c0    = blockIdx.x * 16;          // 16 exclusive cols
    const int sub   = t & 3;                    // which f32x4 chunk of the 16
    const int rbase = t >> 2;                   // 64 row streams
    const int lane  = t & 63;
    const int wave  = t >> 6;

    f32x4 acc = {0.f, 0.f, 0.f, 0.f};
#pragma unroll 8
    for (int k = 0; k < 64; ++k) {
        acc += ntload4(&W[(size_t)(rbase + 64 * k) * N_COLS + c0 + sub * 4]);
    }
    // Reduce across the 16 row-streams within the wave (lanes ≡ sub mod 4).
#pragma unroll
    for (int off = 32; off >= 4; off >>= 1) {
        acc.x += __shfl_down(acc.x, off, 64);
        acc.y += __shfl_down(acc.y, off, 64);
        acc.z += __shfl_down(acc.z, off, 64);
        acc.w += __shfl_down(acc.w, off, 64);
    }
    __shared__ f32x4 red[4][4];
    if (lane < 4) red[wave][lane] = acc;
    __syncthreads();
    if (t < 4) {
        const f32x4 s = red[0][t] + red[1][t] + red[2][t] + red[3][t];
        *reinterpret_cast<f32x4*>(&ws[c0 + t * 4]) = s;
    }
}

// ---------------- Kernel 2: out[b] = SCALE * dot(x[b,:], ws) ----------------
// EXACT R3 version. 4 rows/wave, 4 waves/block, 1024 blocks.
__global__ __launch_bounds__(256) void rowdot_kernel(const float* __restrict__ x,
                                                     const float* __restrict__ ws,
                                                     float* __restrict__ out) {
    const int wave = threadIdx.x >> 6;
    const int lane = threadIdx.x & 63;
    const int row0 = (blockIdx.x * 4 + wave) * 4;   // 4 consecutive rows

    const float* __restrict__ x0 = x + (size_t)(row0 + 0) * N_COLS;
    const float* __restrict__ x1 = x + (size_t)(row0 + 1) * N_COLS;
    const float* __restrict__ x2 = x + (size_t)(row0 + 2) * N_COLS;
    const float* __restrict__ x3 = x + (size_t)(row0 + 3) * N_COLS;

    float a0 = 0.f, a1 = 0.f, a2 = 0.f, a3 = 0.f;
#pragma unroll 8
    for (int i = 0; i < 16; ++i) {
        const int idx = (i * 64 + lane) * 4;
        const f32x4 c  = *reinterpret_cast<const f32x4*>(&ws[idx]); // L1-resident
        const f32x4 v0 = ntload4(&x0[idx]);
        const f32x4 v1 = ntload4(&x1[idx]);
        const f32x4 v2 = ntload4(&x2[idx]);
        const f32x4 v3 = ntload4(&x3[idx]);
        a0 += v0.x * c.x + v0.y * c.y + v0.z * c.z + v0.w * c.w;
        a1 += v1.x * c.x + v1.y * c.y + v1.z * c.z + v1.w * c.w;
        a2 += v2.x * c.x + v2.y * c.y + v2.z * c.z + v2.w * c.w;
        a3 += v3.x * c.x + v3.y * c.y + v3.z * c.z + v3.w * c.w;
    }
#pragma unroll
    for (int off = 32; off >= 1; off >>= 1) {
        a0 += __shfl_down(a0, off, 64);
        a1 += __shfl_down(a1, off, 64);
        a2 += __shfl_down(a2, off, 64);
        a3 += __shfl_down(a3, off, 64);
    }
    if (lane == 0) {
        f32x4 r = {a0 * SCALE, a1 * SCALE, a2 * SCALE, a3 * SCALE};
        *reinterpret_cast<f32x4*>(&out[row0]) = r;
    }
}

extern "C" void kernel_launch(void* const* d_in, const int* in_sizes, int n_in,
                              void* d_out, int out_size, void* d_ws, size_t ws_size,
                              hipStream_t stream) {
    const float* x = (const float*)d_in[0];   // (16384, 4096)
    const float* W = (const float*)d_in[1];   // (4096, 4096)
    float* out = (float*)d_out;               // (16384, 1)
    float* ws  = (float*)d_ws;

    colsum_ex_kernel<<<256, 256, 0, stream>>>(W, ws);
    rowdot_kernel<<<BATCH / 16, 256, 0, stream>>>(x, ws, out);
}

// Round 6
// 68.692 us; speedup vs baseline: 1.3503x; 1.1412x over previous
//
#include <hip/hip_runtime.h>

// x (16384 x 4096 fp32), W (4096 x 4096 fp32)
// out[b] = 0.75 * dot(x[b,:], colsum(W)), shape (16384,1) fp32.
// Memory-bound: 320 MB compulsory read -> ~51 us roofline @ 6.3 TB/s.

#define N_COLS 4096
#define BATCH  16384
#define SCALE  0.75f   // SCALING_FACTOR / 2.0

typedef float f32x4 __attribute__((ext_vector_type(4)));

__device__ __forceinline__ f32x4 ntload4(const float* p) {
    return __builtin_nontemporal_load(reinterpret_cast<const f32x4*>(p));
}

// ---------------- Kernel 1: column-sum of W into ws[0..4095] ----------------
// EXACT R5 version (unchanged this round). Exclusive 16-col tiles, no atomics.
__global__ __launch_bounds__(256) void colsum_ex_kernel(const float* __restrict__ W,
                                                        float* __restrict__ ws) {
    const int t     = threadIdx.x;
    const int c0    = blockIdx.x * 16;          // 16 exclusive cols
    const int sub   = t & 3;                    // which f32x4 chunk of the 16
    const int rbase = t >> 2;                   // 64 row streams
    const int lane  = t & 63;
    const int wave  = t >> 6;

    f32x4 acc = {0.f, 0.f, 0.f, 0.f};
#pragma unroll 8
    for (int k = 0; k < 64; ++k) {
        acc += ntload4(&W[(size_t)(rbase + 64 * k) * N_COLS + c0 + sub * 4]);
    }
#pragma unroll
    for (int off = 32; off >= 4; off >>= 1) {
        acc.x += __shfl_down(acc.x, off, 64);
        acc.y += __shfl_down(acc.y, off, 64);
        acc.z += __shfl_down(acc.z, off, 64);
        acc.w += __shfl_down(acc.w, off, 64);
    }
    __shared__ f32x4 red[4][4];
    if (lane < 4) red[wave][lane] = acc;
    __syncthreads();
    if (t < 4) {
        const f32x4 s = red[0][t] + red[1][t] + red[2][t] + red[3][t];
        *reinterpret_cast<f32x4*>(&ws[c0 + t * 4]) = s;
    }
}

// ---------------- Kernel 2: out[b] = SCALE * dot(x[b,:], ws) ----------------
// v2: MLP by construction. Each wave owns a full row (2 rows sequentially).
// ws is hoisted into 16 persistent f32x4 registers (loaded once, L1/L2-hit).
// Per row: 16 INDEPENDENT nt loads issued as a flat batch (16 KB in flight
// per wave), then the dot + wave reduction. No interleaved consumers.
__global__ __launch_bounds__(256) void rowdot2_kernel(const float* __restrict__ x,
                                                      const float* __restrict__ ws,
                                                      float* __restrict__ out) {
    const int lane = threadIdx.x & 63;
    const int wid  = blockIdx.x * 4 + (threadIdx.x >> 6);   // 0..8191

    f32x4 c[16];
#pragma unroll
    for (int i = 0; i < 16; ++i)
        c[i] = *reinterpret_cast<const f32x4*>(&ws[(i * 64 + lane) * 4]);

#pragma unroll
    for (int rep = 0; rep < 2; ++rep) {
        const int row = wid + rep * 8192;
        const float* __restrict__ xr = x + (size_t)row * N_COLS;

        f32x4 v[16];
#pragma unroll
        for (int i = 0; i < 16; ++i)
            v[i] = ntload4(&xr[(i * 64 + lane) * 4]);

        float acc = 0.f;
#pragma unroll
        for (int i = 0; i < 16; ++i)
            acc += v[i].x * c[i].x + v[i].y * c[i].y +
                   v[i].z * c[i].z + v[i].w * c[i].w;

#pragma unroll
        for (int off = 32; off >= 1; off >>= 1)
            acc += __shfl_down(acc, off, 64);

        if (lane == 0) out[row] = acc * SCALE;
    }
}

extern "C" void kernel_launch(void* const* d_in, const int* in_sizes, int n_in,
                              void* d_out, int out_size, void* d_ws, size_t ws_size,
                              hipStream_t stream) {
    const float* x = (const float*)d_in[0];   // (16384, 4096)
    const float* W = (const float*)d_in[1];   // (4096, 4096)
    float* out = (float*)d_out;               // (16384, 1)
    float* ws  = (float*)d_ws;

    colsum_ex_kernel<<<256, 256, 0, stream>>>(W, ws);
    rowdot2_kernel<<<2048, 256, 0, stream>>>(x, ws, out);
}